// Round 3
// baseline (206.281 us; speedup 1.0000x reference)
//
#include <hip/hip_runtime.h>

// YOLOv1 loss: B=16384, S=7, C=30. Memory-bound streaming reduction.
// One thread per grid cell; float2 loads (cell stride 120 B is 8B-aligned,
// so float4 would be misaligned for odd cells).

#define NCELLS (16384 * 49)
#define INV_NB (1.0f / 16384.0f)

__device__ __forceinline__ float iou_xyxy(float ax1, float ay1, float ax2, float ay2,
                                          float bx1, float by1, float bx2, float by2) {
    float ix1 = fmaxf(ax1, bx1);
    float iy1 = fmaxf(ay1, by1);
    float ix2 = fminf(ax2, bx2);
    float iy2 = fminf(ay2, by2);
    float iw = fmaxf(ix2 - ix1, 0.0f);
    float ih = fmaxf(iy2 - iy1, 0.0f);
    float inter = iw * ih;
    float a1 = (ax2 - ax1) * (ay2 - ay1);
    float a2 = (bx2 - bx1) * (by2 - by1);
    float uni = a1 + a2 - inter;
    return (inter > 0.0f) ? (inter / uni) : 0.0f;
}

__global__ __launch_bounds__(256) void yolo_loss_kernel(const float* __restrict__ pred,
                                                        const float* __restrict__ labels,
                                                        float* __restrict__ out) {
    int cell = blockIdx.x * blockDim.x + threadIdx.x;

    float per = 0.0f;
    if (cell < NCELLS) {
        int rem = cell % 49;
        float fm = (float)(rem / 7);   // axis-1 index -> mg
        float fn = (float)(rem % 7);   // axis-2 index -> ng

        const float2* p2 = reinterpret_cast<const float2*>(pred + (size_t)cell * 30);
        const float2* l2 = reinterpret_cast<const float2*>(labels + (size_t)cell * 30);

        float pv[30], lv[30];
#pragma unroll
        for (int k = 0; k < 15; ++k) {
            float2 a = p2[k];
            pv[2 * k] = a.x; pv[2 * k + 1] = a.y;
        }
#pragma unroll
        for (int k = 0; k < 15; ++k) {
            float2 b = l2[k];
            lv[2 * k] = b.x; lv[2 * k + 1] = b.y;
        }

        // boxes (faithful to reference: /7 for x, /30 for y — the GY bug)
        // pred box 1
        float cx = (pv[0] + fm) / 7.0f;
        float cy = (pv[1] + fn) / 30.0f;
        float w = pv[2], h = pv[3];
        float p1x1 = cx - w * 0.5f, p1y1 = cy - h * 0.5f;
        float p1x2 = cx + w * 0.5f, p1y2 = cy + h * 0.5f;
        // pred box 2
        cx = (pv[5] + fm) / 7.0f;
        cy = (pv[6] + fn) / 30.0f;
        w = pv[7]; h = pv[8];
        float p2x1 = cx - w * 0.5f, p2y1 = cy - h * 0.5f;
        float p2x2 = cx + w * 0.5f, p2y2 = cy + h * 0.5f;
        // gt box
        cx = (lv[0] + fm) / 7.0f;
        cy = (lv[1] + fn) / 30.0f;
        w = lv[2]; h = lv[3];
        float gx1 = cx - w * 0.5f, gy1 = cy - h * 0.5f;
        float gx2 = cx + w * 0.5f, gy2 = cy + h * 0.5f;

        float iou1 = iou_xyxy(p1x1, p1y1, p1x2, p1y2, gx1, gy1, gx2, gy2);
        float iou2 = iou_xyxy(p2x1, p2y1, p2x2, p2y2, gx1, gy1, gx2, gy2);

        bool sel1 = (iou1 >= iou2);
        bool obj = (lv[4] == 1.0f);

        float dx = pv[0] - lv[0], dy = pv[1] - lv[1];
        float dw = sqrtf(pv[2]) - sqrtf(lv[2]);
        float dh = sqrtf(pv[3]) - sqrtf(lv[3]);
        float coor1 = dx * dx + dy * dy + dw * dw + dh * dh;

        dx = pv[5] - lv[5]; dy = pv[6] - lv[6];
        dw = sqrtf(pv[7]) - sqrtf(lv[7]);
        dh = sqrtf(pv[8]) - sqrtf(lv[8]);
        float coor2 = dx * dx + dy * dy + dw * dw + dh * dh;

        float coor = 5.0f * (sel1 ? coor1 : coor2);

        float d1 = pv[4] - iou1; d1 *= d1;
        float d2 = pv[9] - iou2; d2 *= d2;
        float obj_confi = sel1 ? d1 : d2;
        float noobj_at_obj = 0.5f * (sel1 ? d2 : d1);

        float cls = 0.0f;
#pragma unroll
        for (int k = 10; k < 30; ++k) {
            float d = pv[k] - lv[k];
            cls += d * d;
        }

        float noobj_at_noobj = 0.5f * (pv[4] * pv[4] + pv[9] * pv[9]);

        per = obj ? (coor + obj_confi + noobj_at_obj + cls) : noobj_at_noobj;
    }

    // wave64 down-reduce
    float acc = per;
#pragma unroll
    for (int off = 32; off > 0; off >>= 1) acc += __shfl_down(acc, off, 64);

    __shared__ float sbuf[4];
    int lane = threadIdx.x & 63;
    int wid = threadIdx.x >> 6;
    if (lane == 0) sbuf[wid] = acc;
    __syncthreads();
    if (threadIdx.x == 0) {
        float s = (sbuf[0] + sbuf[1] + sbuf[2] + sbuf[3]) * INV_NB;
        atomicAdd(out, s);
    }
}

extern "C" void kernel_launch(void* const* d_in, const int* in_sizes, int n_in,
                              void* d_out, int out_size, void* d_ws, size_t ws_size,
                              hipStream_t stream) {
    const float* pred = (const float*)d_in[0];
    const float* labels = (const float*)d_in[1];
    float* out = (float*)d_out;

    // d_out is poisoned to 0xAA before every launch — zero it (capture-safe).
    hipMemsetAsync(out, 0, sizeof(float), stream);

    const int threads = 256;
    const int blocks = (NCELLS + threads - 1) / threads;  // = 3136 exactly
    yolo_loss_kernel<<<blocks, threads, 0, stream>>>(pred, labels, out);
}

// Round 5
// 203.960 us; speedup vs baseline: 1.0114x; 1.0114x over previous
//
#include <hip/hip_runtime.h>

// YOLOv1 loss: B=16384, S=7, C=30. Round-3 profile: NOT HBM-bound (replay
// dispatches run 74.6us with ~0 HBM traffic). Bottleneck = address divergence:
// AoS stride-120B float2 loads -> ~60 cache-line requests per wave-instr.
// Fix: coalesced float4 staging of 256-cell slabs into LDS (60KB/block),
// then per-thread LDS reads. 2 blocks/CU (LDS-capped).

#define NCELLS (16384 * 49)
#define INV_NB (1.0f / 16384.0f)
#define CPB 256                    // cells per block
#define FPA (CPB * 30)             // floats per array slab = 7680
#define F4PA (FPA / 4)             // float4 per array slab = 1920

__device__ __forceinline__ float iou_xyxy(float ax1, float ay1, float ax2, float ay2,
                                          float bx1, float by1, float bx2, float by2) {
    float ix1 = fmaxf(ax1, bx1);
    float iy1 = fmaxf(ay1, by1);
    float ix2 = fminf(ax2, bx2);
    float iy2 = fminf(ay2, by2);
    float iw = fmaxf(ix2 - ix1, 0.0f);
    float ih = fmaxf(iy2 - iy1, 0.0f);
    float inter = iw * ih;
    float a1 = (ax2 - ax1) * (ay2 - ay1);
    float a2 = (bx2 - bx1) * (by2 - by1);
    float uni = a1 + a2 - inter;
    return (inter > 0.0f) ? (inter / uni) : 0.0f;
}

__global__ __launch_bounds__(256, 2) void yolo_loss_kernel(const float* __restrict__ pred,
                                                           const float* __restrict__ labels,
                                                           float* __restrict__ out) {
    __shared__ float sm[2 * FPA];  // [0,7680) = pred slab, [7680,15360) = labels slab

    const int t = threadIdx.x;
    const float* gp = pred + (size_t)blockIdx.x * FPA;
    const float* gl = labels + (size_t)blockIdx.x * FPA;

    // ---- coalesced staging: 3840 float4 total, 15 rounds of 256 lanes ----
    float4* sm4 = reinterpret_cast<float4*>(sm);
    const float4* gp4 = reinterpret_cast<const float4*>(gp);
    const float4* gl4 = reinterpret_cast<const float4*>(gl);
#pragma unroll
    for (int i = 0; i < 15; ++i) {
        int idx = i * 256 + t;                       // float4 index in [0, 3840)
        float4 v = (idx < F4PA) ? gp4[idx] : gl4[idx - F4PA];
        sm4[idx] = v;
    }
    __syncthreads();

    // ---- per-cell loss from LDS (thread t owns local cell t) ----
    const int gcell = blockIdx.x * CPB + t;          // < NCELLS exactly (3136*256)
    const int rem = gcell % 49;
    const float fm = (float)(rem / 7);               // axis-1 index -> mg
    const float fn = (float)(rem % 7);               // axis-2 index -> ng

    // t*30 floats = t*120 B: 8B-aligned -> float2 LDS reads
    const float2* ps = reinterpret_cast<const float2*>(sm + t * 30);
    const float2* ls = reinterpret_cast<const float2*>(sm + FPA + t * 30);

    float pv[30], lv[30];
#pragma unroll
    for (int k = 0; k < 15; ++k) {
        float2 a = ps[k];
        pv[2 * k] = a.x; pv[2 * k + 1] = a.y;
    }
#pragma unroll
    for (int k = 0; k < 15; ++k) {
        float2 b = ls[k];
        lv[2 * k] = b.x; lv[2 * k + 1] = b.y;
    }

    // boxes (faithful to reference: /7 for x, /30 for y — the GY bug)
    float cx = (pv[0] + fm) / 7.0f;
    float cy = (pv[1] + fn) / 30.0f;
    float w = pv[2], h = pv[3];
    float p1x1 = cx - w * 0.5f, p1y1 = cy - h * 0.5f;
    float p1x2 = cx + w * 0.5f, p1y2 = cy + h * 0.5f;

    cx = (pv[5] + fm) / 7.0f;
    cy = (pv[6] + fn) / 30.0f;
    w = pv[7]; h = pv[8];
    float p2x1 = cx - w * 0.5f, p2y1 = cy - h * 0.5f;
    float p2x2 = cx + w * 0.5f, p2y2 = cy + h * 0.5f;

    cx = (lv[0] + fm) / 7.0f;
    cy = (lv[1] + fn) / 30.0f;
    w = lv[2]; h = lv[3];
    float gx1 = cx - w * 0.5f, gy1 = cy - h * 0.5f;
    float gx2 = cx + w * 0.5f, gy2 = cy + h * 0.5f;

    float iou1 = iou_xyxy(p1x1, p1y1, p1x2, p1y2, gx1, gy1, gx2, gy2);
    float iou2 = iou_xyxy(p2x1, p2y1, p2x2, p2y2, gx1, gy1, gx2, gy2);

    bool sel1 = (iou1 >= iou2);
    bool obj = (lv[4] == 1.0f);

    float dx = pv[0] - lv[0], dy = pv[1] - lv[1];
    float dw = sqrtf(pv[2]) - sqrtf(lv[2]);
    float dh = sqrtf(pv[3]) - sqrtf(lv[3]);
    float coor1 = dx * dx + dy * dy + dw * dw + dh * dh;

    dx = pv[5] - lv[5]; dy = pv[6] - lv[6];
    dw = sqrtf(pv[7]) - sqrtf(lv[7]);
    dh = sqrtf(pv[8]) - sqrtf(lv[8]);
    float coor2 = dx * dx + dy * dy + dw * dw + dh * dh;

    float coor = 5.0f * (sel1 ? coor1 : coor2);

    float d1 = pv[4] - iou1; d1 *= d1;
    float d2 = pv[9] - iou2; d2 *= d2;
    float obj_confi = sel1 ? d1 : d2;
    float noobj_at_obj = 0.5f * (sel1 ? d2 : d1);

    float cls = 0.0f;
#pragma unroll
    for (int k = 10; k < 30; ++k) {
        float d = pv[k] - lv[k];
        cls += d * d;
    }

    float noobj_at_noobj = 0.5f * (pv[4] * pv[4] + pv[9] * pv[9]);

    float per = obj ? (coor + obj_confi + noobj_at_obj + cls) : noobj_at_noobj;

    // ---- wave64 reduce, then block reduce, one atomic per block ----
    float acc = per;
#pragma unroll
    for (int off = 32; off > 0; off >>= 1) acc += __shfl_down(acc, off, 64);

    __shared__ float sbuf[4];
    int lane = t & 63;
    int wid = t >> 6;
    if (lane == 0) sbuf[wid] = acc;
    __syncthreads();
    if (t == 0) {
        float s = (sbuf[0] + sbuf[1] + sbuf[2] + sbuf[3]) * INV_NB;
        atomicAdd(out, s);
    }
}

extern "C" void kernel_launch(void* const* d_in, const int* in_sizes, int n_in,
                              void* d_out, int out_size, void* d_ws, size_t ws_size,
                              hipStream_t stream) {
    const float* pred = (const float*)d_in[0];
    const float* labels = (const float*)d_in[1];
    float* out = (float*)d_out;

    // d_out is poisoned to 0xAA before every launch — zero it (capture-safe).
    hipMemsetAsync(out, 0, sizeof(float), stream);

    const int threads = 256;
    const int blocks = NCELLS / threads;  // 3136 exactly
    yolo_loss_kernel<<<blocks, threads, 0, stream>>>(pred, labels, out);
}

// Round 6
// 203.212 us; speedup vs baseline: 1.0151x; 1.0037x over previous
//
#include <hip/hip_runtime.h>

// YOLOv1 loss: B=16384, S=7, C=30.
// R3: AoS stride-120B direct loads -> TA-divergence bound, 75us.
// R5: 256-cell LDS slab (60.5KB) -> occupancy 14.5%, latency-serialized, 72us.
// R6: 1-wave blocks, 64-cell slabs (15.36KB LDS) -> 10 blocks/CU, deep MLP,
//     no same-address atomics (partials + reduce kernel).

#define NCELLS (16384 * 49)
#define INV_NB (1.0f / 16384.0f)
#define CPB 64                       // cells per block (= 1 wave)
#define NBLK (NCELLS / CPB)          // 12544
#define SLAB_F4 (CPB * 30 / 4)       // 480 float4 per array slab
#define SLAB_F (CPB * 30)            // 1920 floats per array slab

__device__ __forceinline__ float iou_xyxy(float ax1, float ay1, float ax2, float ay2,
                                          float bx1, float by1, float bx2, float by2) {
    float ix1 = fmaxf(ax1, bx1);
    float iy1 = fmaxf(ay1, by1);
    float ix2 = fminf(ax2, bx2);
    float iy2 = fminf(ay2, by2);
    float iw = fmaxf(ix2 - ix1, 0.0f);
    float ih = fmaxf(iy2 - iy1, 0.0f);
    float inter = iw * ih;
    float a1 = (ax2 - ax1) * (ay2 - ay1);
    float a2 = (bx2 - bx1) * (by2 - by1);
    float uni = a1 + a2 - inter;
    return (inter > 0.0f) ? (inter / uni) : 0.0f;
}

__global__ __launch_bounds__(64, 2) void yolo_loss_stage1(const float* __restrict__ pred,
                                                          const float* __restrict__ labels,
                                                          float* __restrict__ partials) {
    __shared__ float sm[2 * SLAB_F];   // [0,1920) pred, [1920,3840) labels

    const int t = threadIdx.x;         // 0..63
    const int b = blockIdx.x;

    // ---- coalesced staging: issue ALL 15 float4 loads, then 15 LDS writes ----
    const float4* gp4 = reinterpret_cast<const float4*>(pred) + (size_t)b * SLAB_F4;
    const float4* gl4 = reinterpret_cast<const float4*>(labels) + (size_t)b * SLAB_F4;

    float4 r[15];
#pragma unroll
    for (int i = 0; i < 15; ++i) {
        int idx = i * 64 + t;                        // float4 idx in [0,960)
        r[i] = (idx < SLAB_F4) ? gp4[idx] : gl4[idx - SLAB_F4];
    }
    float4* sm4 = reinterpret_cast<float4*>(sm);
#pragma unroll
    for (int i = 0; i < 15; ++i) {
        sm4[i * 64 + t] = r[i];
    }
    __syncthreads();   // 1-wave block: compiles to lgkmcnt wait + trivial barrier

    // ---- per-cell loss from LDS ----
    const int gcell = b * CPB + t;
    const int rem = gcell % 49;
    const float fm = (float)(rem / 7);               // axis-1 index -> mg
    const float fn = (float)(rem % 7);               // axis-2 index -> ng

    const float2* ps = reinterpret_cast<const float2*>(sm + t * 30);
    const float2* ls = reinterpret_cast<const float2*>(sm + SLAB_F + t * 30);

    float pv[30], lv[30];
#pragma unroll
    for (int k = 0; k < 15; ++k) {
        float2 a = ps[k];
        pv[2 * k] = a.x; pv[2 * k + 1] = a.y;
    }
#pragma unroll
    for (int k = 0; k < 15; ++k) {
        float2 bb = ls[k];
        lv[2 * k] = bb.x; lv[2 * k + 1] = bb.y;
    }

    // boxes (faithful to reference: /7 for x, /30 for y — the GY bug)
    float cx = (pv[0] + fm) / 7.0f;
    float cy = (pv[1] + fn) / 30.0f;
    float w = pv[2], h = pv[3];
    float p1x1 = cx - w * 0.5f, p1y1 = cy - h * 0.5f;
    float p1x2 = cx + w * 0.5f, p1y2 = cy + h * 0.5f;

    cx = (pv[5] + fm) / 7.0f;
    cy = (pv[6] + fn) / 30.0f;
    w = pv[7]; h = pv[8];
    float p2x1 = cx - w * 0.5f, p2y1 = cy - h * 0.5f;
    float p2x2 = cx + w * 0.5f, p2y2 = cy + h * 0.5f;

    cx = (lv[0] + fm) / 7.0f;
    cy = (lv[1] + fn) / 30.0f;
    w = lv[2]; h = lv[3];
    float gx1 = cx - w * 0.5f, gy1 = cy - h * 0.5f;
    float gx2 = cx + w * 0.5f, gy2 = cy + h * 0.5f;

    float iou1 = iou_xyxy(p1x1, p1y1, p1x2, p1y2, gx1, gy1, gx2, gy2);
    float iou2 = iou_xyxy(p2x1, p2y1, p2x2, p2y2, gx1, gy1, gx2, gy2);

    bool sel1 = (iou1 >= iou2);
    bool obj = (lv[4] == 1.0f);

    float dx = pv[0] - lv[0], dy = pv[1] - lv[1];
    float dw = sqrtf(pv[2]) - sqrtf(lv[2]);
    float dh = sqrtf(pv[3]) - sqrtf(lv[3]);
    float coor1 = dx * dx + dy * dy + dw * dw + dh * dh;

    dx = pv[5] - lv[5]; dy = pv[6] - lv[6];
    dw = sqrtf(pv[7]) - sqrtf(lv[7]);
    dh = sqrtf(pv[8]) - sqrtf(lv[8]);
    float coor2 = dx * dx + dy * dy + dw * dw + dh * dh;

    float coor = 5.0f * (sel1 ? coor1 : coor2);

    float d1 = pv[4] - iou1; d1 *= d1;
    float d2 = pv[9] - iou2; d2 *= d2;
    float obj_confi = sel1 ? d1 : d2;
    float noobj_at_obj = 0.5f * (sel1 ? d2 : d1);

    float cls = 0.0f;
#pragma unroll
    for (int k = 10; k < 30; ++k) {
        float d = pv[k] - lv[k];
        cls += d * d;
    }

    float noobj_at_noobj = 0.5f * (pv[4] * pv[4] + pv[9] * pv[9]);

    float per = obj ? (coor + obj_confi + noobj_at_obj + cls) : noobj_at_noobj;

    // ---- wave64 reduce; one plain store per block (no atomics) ----
    float acc = per;
#pragma unroll
    for (int off = 32; off > 0; off >>= 1) acc += __shfl_down(acc, off, 64);
    if (t == 0) partials[b] = acc;
}

__global__ __launch_bounds__(256) void yolo_loss_stage2(const float* __restrict__ partials,
                                                        float* __restrict__ out) {
    const int t = threadIdx.x;
    float acc = 0.0f;
#pragma unroll
    for (int i = 0; i < NBLK / 256; ++i) {          // 49 iters, coalesced
        acc += partials[i * 256 + t];
    }
#pragma unroll
    for (int off = 32; off > 0; off >>= 1) acc += __shfl_down(acc, off, 64);

    __shared__ float sbuf[4];
    if ((t & 63) == 0) sbuf[t >> 6] = acc;
    __syncthreads();
    if (t == 0) out[0] = (sbuf[0] + sbuf[1] + sbuf[2] + sbuf[3]) * INV_NB;
}

extern "C" void kernel_launch(void* const* d_in, const int* in_sizes, int n_in,
                              void* d_out, int out_size, void* d_ws, size_t ws_size,
                              hipStream_t stream) {
    const float* pred = (const float*)d_in[0];
    const float* labels = (const float*)d_in[1];
    float* out = (float*)d_out;
    float* partials = (float*)d_ws;    // 12544 floats = 50 KB, well under ws_size

    yolo_loss_stage1<<<NBLK, 64, 0, stream>>>(pred, labels, partials);
    yolo_loss_stage2<<<1, 256, 0, stream>>>(partials, out);
}